// Round 6
// baseline (247.546 us; speedup 1.0000x reference)
//
#include <hip/hip_runtime.h>
#include <hip/hip_bf16.h>

// Problem constants
#define B   256
#define N   100
#define D   768
#define R   80
#define THRESHOLD 0.5f

// Native clang vector type (required by __builtin_nontemporal_*)
typedef float v4f __attribute__((ext_vector_type(4)));

// Output layout (flat float32 offsets, in return order)
#define SZ_VIS    ((long)B * R * D)            // 15,728,640
#define OFF_VIS   0L
#define OFF_TXT   (OFF_VIS + SZ_VIS)           // 15,728,640
#define OFF_TMASK (OFF_TXT + SZ_VIS)           // 31,457,280
#define OFF_IMASK (OFF_TMASK + (long)B*(R+1))  // 31,478,016
#define OFF_RR    (OFF_IMASK + (long)B*(R+1))  // 31,498,752
#define OFF_LAB   (OFF_RR + (long)B*R)         // 31,519,232

// Kernel 1: per-batch control logic + all small outputs.
// One block per batch, 128 threads; thread 0 does the 80-elem stable
// partition (== stable argsort of (1-binary)). Cheap: 256 blocks total.
__global__ __launch_bounds__(128) void prep_kernel(
    const float* __restrict__ rr_in,    // (B, N)
    const float* __restrict__ lab_in,   // (B, N)
    float* __restrict__ out,
    int* __restrict__ order,            // (B, R) ws
    int* __restrict__ counts)           // (B,)   ws
{
    const int b = blockIdx.x;
    const int t = threadIdx.x;

    __shared__ float rrs[R];
    __shared__ int   cnt_s;
    __shared__ int   zero_s;

    if (t < R) rrs[t] = rr_in[b * N + t];
    __syncthreads();

    if (t == 0) {
        int c = 0;
        int allz = 1;   // zero_rows <=> all rr < 0.5
        for (int i = 0; i < R; ++i) {
            float v = rrs[i];
            if (v >= THRESHOLD) allz = 0;
            if (v > THRESHOLD) order[b * R + c++] = i;
        }
        int p = c;
        for (int i = 0; i < R; ++i)
            if (!(rrs[i] > THRESHOLD)) order[b * R + p++] = i;
        counts[b] = c;
        cnt_s  = c;
        zero_s = allz;
    }
    __syncthreads();

    const int cnt = cnt_s;
    if (t < R) {
        out[OFF_LAB + (long)b * R + t] = lab_in[b * N + t];
        float v  = rrs[t];
        float rm = (v < THRESHOLD) ? 0.0f : v;
        if (t == 0 && zero_s) rm = 1.0f;
        out[OFF_RR + (long)b * R + t] = rm;
    }
    if (t <= R) {  // R+1 = 81 mask entries
        float tm = (t <= cnt) ? 1.0f : 0.0f;
        out[OFF_TMASK + (long)b * (R + 1) + t] = tm;
        out[OFF_IMASK + (long)b * (R + 1) + t] = (b == B - 1) ? tm : 1.0f;
    }
}

// Kernel 2: pure streaming gather. 256 threads = 4 waves; each wave owns one
// output row (both tensors): lane l moves float4s {l, l+64, l+128} of the row.
// No LDS, no __syncthreads, wave-uniform count/order loads, low VGPR.
__global__ __launch_bounds__(256) void gather_kernel(
    const float* __restrict__ vis,   // (B, N, 1, D)
    const float* __restrict__ txt,   // (B, N, 1, D)
    float* __restrict__ out,
    const int* __restrict__ order,
    const int* __restrict__ counts)
{
    const int wid  = threadIdx.x >> 6;
    const int lane = threadIdx.x & 63;
    const int row  = blockIdx.x * 4 + wid;      // 0 .. B*R-1
    const int b = row / R;                       // magic-div (const)
    const int r = row - b * R;

    v4f v0 = (v4f){0,0,0,0}, v1 = v0, v2 = v0;
    v4f x0 = v0, x1 = v0, x2 = v0;

    if (r < counts[b]) {                         // uniform per wave
        const int src = order[row];              // wave-uniform
        const long in0 = ((long)b * N + src) * D + lane * 4;
        v0 = *(const v4f*)(vis + in0);
        v1 = *(const v4f*)(vis + in0 + 256);
        v2 = *(const v4f*)(vis + in0 + 512);
        x0 = *(const v4f*)(txt + in0);
        x1 = *(const v4f*)(txt + in0 + 256);
        x2 = *(const v4f*)(txt + in0 + 512);
    }
    const long o = (long)row * D + lane * 4;     // row == b*R + r
    __builtin_nontemporal_store(v0, (v4f*)(out + OFF_VIS + o));
    __builtin_nontemporal_store(v1, (v4f*)(out + OFF_VIS + o + 256));
    __builtin_nontemporal_store(v2, (v4f*)(out + OFF_VIS + o + 512));
    __builtin_nontemporal_store(x0, (v4f*)(out + OFF_TXT + o));
    __builtin_nontemporal_store(x1, (v4f*)(out + OFF_TXT + o + 256));
    __builtin_nontemporal_store(x2, (v4f*)(out + OFF_TXT + o + 512));
}

extern "C" void kernel_launch(void* const* d_in, const int* in_sizes, int n_in,
                              void* d_out, int out_size, void* d_ws, size_t ws_size,
                              hipStream_t stream) {
    // inputs (setup_inputs order):
    // 0: mean_pooling_vec (B,D)        -- unused
    // 1: merge_text_vec (B,D)          -- unused
    // 2: retrieved_visual_feature_embedding_cls (B,N,1,D)
    // 3: retrieved_textual_feature_embedding    (B,N,1,D)
    // 4: retrieved_label_list (B,N)
    // 5: RRCP (B,N)
    const float* vis = (const float*)d_in[2];
    const float* txt = (const float*)d_in[3];
    const float* lab = (const float*)d_in[4];
    const float* rr  = (const float*)d_in[5];
    float* out = (float*)d_out;

    int* order  = (int*)d_ws;            // B*R ints
    int* counts = order + B * R;         // B ints

    prep_kernel<<<B, 128, 0, stream>>>(rr, lab, out, order, counts);
    gather_kernel<<<(B * R) / 4, 256, 0, stream>>>(vis, txt, out, order, counts);
}